// Round 14
// baseline (1448.476 us; speedup 1.0000x reference)
//
#include <hip/hip_runtime.h>
#include <hip/hip_bf16.h>
#include <math.h>

typedef unsigned short u16;
typedef __bf16 bf16x8_t __attribute__((ext_vector_type(8)));
typedef float  f32x4_t  __attribute__((ext_vector_type(4)));
typedef float  f32x8_t  __attribute__((ext_vector_type(8)));
typedef u16    u16x4_t  __attribute__((ext_vector_type(4)));
typedef u16    u16x8_t  __attribute__((ext_vector_type(8)));

// ---------- helpers ----------
__device__ __forceinline__ u16 f2b(float f) {
  unsigned u = __builtin_bit_cast(unsigned, f);
  u += 0x7fffu + ((u >> 16) & 1u);      // RNE; inputs are finite
  return (u16)(u >> 16);
}
__device__ __forceinline__ float b2f(u16 h) {
  unsigned u = ((unsigned)h) << 16;
  return __builtin_bit_cast(float, u);
}
__device__ __forceinline__ float sigm_(float x) { return 1.0f / (1.0f + __expf(-x)); }
__device__ __forceinline__ float tanh_(float x) { return 1.0f - 2.0f / (__expf(2.0f * x) + 1.0f); }

__device__ __forceinline__ void gload16(const void* g, void* l) {
  __builtin_amdgcn_global_load_lds(
      (__attribute__((address_space(1))) void*)(g),
      (__attribute__((address_space(3))) void*)(l), 16, 0, 0);
}

// ==========================================================================
// Packed panel formats (k-plane = 8 consecutive k as 16B per row):
//  256-row tiles: [p 0..3][row 0..255][8 u16] = 8192 u16 (16 KB)
// W2q: 256-col tiles [p 0..3][col 0..255][8 u16] = 8192 u16, [4cg][128kt].
// Staging = contiguous 16B/thread wave loads; LDS image == packed tile ->
// conflict-free ds_read_b128 fragments.
// ==========================================================================

// ---------- single fused pack kernel: grid (100,160), block 256 ----------
// bx 0..63  : activations -> A1p   (mb=bx, kt=by; x 0..63 | h 64..95 | c 96..159)
// bx 64..95 : W1 transpose -> W1tp (nb=bx-64, kt=by)
// bx 96..99 : W2 transpose -> W2q  (cg=bx-96, kt=by<128)
__global__ void pack_all_kernel(const float* __restrict__ x, const float* __restrict__ h,
                                const float* __restrict__ c,
                                const float* __restrict__ w_if_x, const float* __restrict__ w_if_h,
                                const float* __restrict__ w_if_c, const float* __restrict__ w_c_x,
                                const float* __restrict__ w_c_h,  const float* __restrict__ w_o_x,
                                const float* __restrict__ w_o_h,  const float* __restrict__ w_r_x,
                                const float* __restrict__ w_o_c,  const float* __restrict__ w_r_proj,
                                u16* __restrict__ A1p, u16* __restrict__ W1tp,
                                u16* __restrict__ W2q) {
  int bx = blockIdx.x, by = blockIdx.y, t = threadIdx.x;

  if (bx < 64) {
    // ---- activation pack ----
    int mb = bx, kt = by;
    const float* src; int C, ccol;
    if (kt < 64)      { src = x; C = 2048; ccol = kt * 32; }
    else if (kt < 96) { src = h; C = 1024; ccol = (kt - 64) * 32; }
    else              { src = c; C = 2048; ccol = (kt - 96) * 32; }
    const float* s = src + (long)(mb * 256 + t) * C + ccol;
    u16* d = A1p + ((long)(mb * 160 + kt)) * 8192 + t * 8;
#pragma unroll
    for (int p = 0; p < 4; ++p) {
      f32x8_t v = *(const f32x8_t*)(s + p * 8);
      u16x8_t o;
#pragma unroll
      for (int r = 0; r < 8; ++r) o[r] = f2b(v[r]);
      *(u16x8_t*)(d + p * 2048) = o;
    }
    return;
  }

  if (bx < 96) {
    // ---- W1 transpose pack ----
    int nb = bx - 64, kt = by;
    int n0g = nb * 256;
    const float* src; int N, nl, kl;
    if (n0g < 4096) {
      N = 4096; nl = n0g;
      if (kt < 64)      { src = w_if_x; kl = kt * 32; }
      else if (kt < 96) { src = w_if_h; kl = (kt - 64) * 32; }
      else              { src = w_if_c; kl = (kt - 96) * 32; }
    } else if (n0g < 6144) {
      N = 2048; nl = n0g - 4096;
      if (kt < 64)      { src = w_c_x; kl = kt * 32; }
      else if (kt < 96) { src = w_c_h; kl = (kt - 64) * 32; }
      else return;
    } else if (n0g < 7168) {
      N = 1024; nl = n0g - 6144;
      if (kt < 64)      { src = w_o_x; kl = kt * 32; }
      else if (kt < 96) { src = w_o_h; kl = (kt - 64) * 32; }
      else return;
    } else {
      N = 1024; nl = n0g - 7168;
      if (kt < 64)      { src = w_r_x; kl = kt * 32; }
      else return;
    }
    int n = nl + t;
    float tmp[32];
#pragma unroll
    for (int kk = 0; kk < 32; ++kk)
      tmp[kk] = src[(long)(kl + kk) * N + n];
    u16* d = W1tp + ((long)(nb * 160 + kt)) * 8192 + t * 8;
#pragma unroll
    for (int p = 0; p < 4; ++p) {
      u16x8_t o;
#pragma unroll
      for (int r = 0; r < 8; ++r) o[r] = f2b(tmp[p * 8 + r]);
      *(u16x8_t*)(d + p * 2048) = o;
    }
    return;
  }

  // ---- W2 transpose pack: 256-col tiles ----
  {
    int cg = bx - 96, kt = by;
    if (kt >= 128) return;
    const float* src; int kl;
    if (kt < 64) { src = w_o_c;    kl = kt * 32; }
    else         { src = w_r_proj; kl = (kt - 64) * 32; }
    int n = cg * 256 + t;
    float tmp[32];
#pragma unroll
    for (int kk = 0; kk < 32; ++kk)
      tmp[kk] = src[(long)(kl + kk) * 1024 + n];
    u16* d = W2q + ((long)(cg * 128 + kt)) * 8192 + t * 8;
#pragma unroll
    for (int p = 0; p < 4; ++p) {
      u16x8_t o;
#pragma unroll
      for (int r = 0; r < 8; ++r) o[r] = f2b(tmp[p * 8 + r]);
      *(u16x8_t*)(d + p * 2048) = o;
    }
  }
}

// ==========================================================================
// GEMM1 (R13-exact): 256x256 bf16, 16x16x32 MFMA, 8 waves (2M x 4N), BK=32,
// 4-slot LDS ring (128KB), stage t+3 split A/B around the MFMA clusters,
// boundary vmcnt(4), mid-tile register prefetch of next tile's fragments.
// Steady ~893us, MfmaUtil ~56.5%.
// ==========================================================================
struct FragSet { bf16x8_t bv[4]; bf16x8_t av[4]; };

__global__ __launch_bounds__(512, 2) void gemm1_kernel(
    const u16* __restrict__ A, const u16* __restrict__ Bt, u16* __restrict__ Cout) {
  constexpr int KTF  = 160;
  constexpr int NCOL = 8192;
  constexpr int NBN  = 32;
  constexpr int SLOT = 16384;   // u16 per ring slot (A 8192 + B 8192)

  __shared__ u16 lds[4 * SLOT];  // 128 KiB

  int bid = blockIdx.x;
  int cpx = gridDim.x >> 3;
  bid = (bid & 7) * cpx + (bid >> 3);

  int mb = bid / NBN, nb = bid % NBN;
  int m0 = mb * 256, n0 = nb * 256;

  int NT = (nb < 16) ? 160 : ((nb < 28) ? 96 : 64);   // always even, >= 64

  const int tid  = threadIdx.x;
  const int lane = tid & 63;
  const int wid  = tid >> 6;
  const int wr   = wid >> 2;       // 0..1
  const int wc   = wid & 3;        // 0..3
  const int hl16 = lane >> 4;      // 0..3 (k-plane)
  const int l15  = lane & 15;

  const int dstg = tid * 8;  // u16
  const u16* pA = A  + ((long)(mb * KTF)) * 8192 + dstg;
  const u16* pB = Bt + ((long)(nb * KTF)) * 8192 + dstg;

#define STAGE_A(t, s) do { \
    gload16(pA + (long)(t) * 8192,        &lds[(s) * SLOT + dstg]); \
    gload16(pA + (long)(t) * 8192 + 4096, &lds[(s) * SLOT + dstg + 4096]); } while (0)
#define STAGE_B(t, s) do { \
    gload16(pB + (long)(t) * 8192,        &lds[(s) * SLOT + 8192 + dstg]); \
    gload16(pB + (long)(t) * 8192 + 4096, &lds[(s) * SLOT + 8192 + dstg + 4096]); } while (0)

  const int aoff = hl16 * 2048 + (wr * 128 + l15) * 8;  // + m*128 (16 rows)
  const int boff = hl16 * 2048 + (wc * 64  + l15) * 8;  // + n*128

#define RD_P(S, si) do { \
    const u16* _pb = &lds[(si) * SLOT]; \
    const u16* _pc = _pb + 8192; \
    _Pragma("unroll") \
    for (int n = 0; n < 4; ++n) S.bv[n] = *(const bf16x8_t*)&_pc[boff + n * 128]; \
    _Pragma("unroll") \
    for (int m = 0; m < 4; ++m) S.av[m] = *(const bf16x8_t*)&_pb[aoff + m * 128]; } while (0)

#define ITER(TT, P, N) do { \
    const int _t = (TT); \
    const u16* _sb = &lds[(_t & 3) * SLOT]; \
    const bool _p3 = (_t + 3 < NT); \
    if (_p3) STAGE_A(_t + 3, (_t + 3) & 3); \
    bf16x8_t _aq0 = *(const bf16x8_t*)&_sb[aoff + 4 * 128]; \
    bf16x8_t _aq1 = *(const bf16x8_t*)&_sb[aoff + 5 * 128]; \
    bf16x8_t _aq2 = *(const bf16x8_t*)&_sb[aoff + 6 * 128]; \
    bf16x8_t _aq3 = *(const bf16x8_t*)&_sb[aoff + 7 * 128]; \
    __builtin_amdgcn_s_setprio(1); \
    _Pragma("unroll") \
    for (int m = 0; m < 4; ++m) \
      _Pragma("unroll") \
      for (int n = 0; n < 4; ++n) \
        acc[m][n] = __builtin_amdgcn_mfma_f32_16x16x32_bf16(P.bv[n], P.av[m], acc[m][n], 0, 0, 0); \
    __builtin_amdgcn_s_setprio(0); \
    if (_p3) STAGE_B(_t + 3, (_t + 3) & 3); \
    if (_t + 1 < NT) RD_P(N, (_t + 1) & 3); \
    __builtin_amdgcn_s_setprio(1); \
    _Pragma("unroll") \
    for (int n = 0; n < 4; ++n) { \
      acc[4][n] = __builtin_amdgcn_mfma_f32_16x16x32_bf16(P.bv[n], _aq0, acc[4][n], 0, 0, 0); \
      acc[5][n] = __builtin_amdgcn_mfma_f32_16x16x32_bf16(P.bv[n], _aq1, acc[5][n], 0, 0, 0); \
      acc[6][n] = __builtin_amdgcn_mfma_f32_16x16x32_bf16(P.bv[n], _aq2, acc[6][n], 0, 0, 0); \
      acc[7][n] = __builtin_amdgcn_mfma_f32_16x16x32_bf16(P.bv[n], _aq3, acc[7][n], 0, 0, 0); \
    } \
    __builtin_amdgcn_s_setprio(0); \
    if (_p3) asm volatile("s_waitcnt vmcnt(4)" ::: "memory"); \
    else     asm volatile("s_waitcnt vmcnt(0)" ::: "memory"); \
    __builtin_amdgcn_s_barrier(); \
  } while (0)

  f32x4_t acc[8][4];
#pragma unroll
  for (int m = 0; m < 8; ++m)
#pragma unroll
    for (int n = 0; n < 4; ++n) acc[m][n] = (f32x4_t){0.f, 0.f, 0.f, 0.f};

  STAGE_A(0, 0); STAGE_B(0, 0);
  STAGE_A(1, 1); STAGE_B(1, 1);
  STAGE_A(2, 2); STAGE_B(2, 2);
  asm volatile("s_waitcnt vmcnt(4)" ::: "memory");
  __builtin_amdgcn_s_barrier();

  FragSet FA, FB;
  RD_P(FA, 0);

  for (int t = 0; t < NT; t += 2) {
    ITER(t,     FA, FB);
    ITER(t + 1, FB, FA);
  }
#undef STAGE_A
#undef STAGE_B
#undef RD_P
#undef ITER

  const int rowm = lane & 15;
  const int col4 = (lane >> 4) * 4;
#pragma unroll
  for (int m = 0; m < 8; ++m) {
    long rg = (long)(m0 + wr * 128 + m * 16 + rowm) * NCOL;
#pragma unroll
    for (int n = 0; n < 4; ++n) {
      int cg = n0 + wc * 64 + n * 16 + col4;
      u16x4_t o;
#pragma unroll
      for (int r = 0; r < 4; ++r) o[r] = f2b(acc[m][n][r]);
      *(u16x4_t*)&Cout[rg + cg] = o;
    }
  }
}

// ---------- pass2: gates -> c_new (fp32), A2 packed = [bf16(c_new) | bf16(tanh(c_new))] ----------
__global__ void pass2_kernel(const u16* __restrict__ G1, const float* __restrict__ c_t,
                             const float* __restrict__ bias_i, const float* __restrict__ bias_f,
                             const float* __restrict__ bias_c,
                             float* __restrict__ c_new_out, u16* __restrict__ A2p) {
  int mb = blockIdx.x, jg = blockIdx.y, t = threadIdx.x;
  int b = mb * 256 + t;
  int j0 = jg * 32;
  const u16* row = G1 + (long)b * 8192 + j0;
  const float* cp_p = c_t + (long)b * 2048 + j0;
  float* co_p = c_new_out + (long)b * 2048 + j0;
  u16* dc = A2p + ((long)(mb * 128 + jg)) * 8192 + t * 8;
  u16* dr = dc + (long)64 * 8192;

#pragma unroll
  for (int q = 0; q < 4; ++q) {
    u16x8_t ip = *(const u16x8_t*)(row + q * 8);
    u16x8_t fp = *(const u16x8_t*)(row + 2048 + q * 8);
    u16x8_t gp = *(const u16x8_t*)(row + 4096 + q * 8);
    f32x8_t cp = *(const f32x8_t*)(cp_p + q * 8);
    f32x8_t bi = *(const f32x8_t*)(bias_i + j0 + q * 8);
    f32x8_t bf = *(const f32x8_t*)(bias_f + j0 + q * 8);
    f32x8_t bc = *(const f32x8_t*)(bias_c + j0 + q * 8);
    f32x8_t cn;
    u16x8_t cb, rb;
#pragma unroll
    for (int r = 0; r < 8; ++r) {
      float ig = sigm_(b2f(ip[r]) + bi[r]);
      float fg = sigm_(b2f(fp[r]) + bf[r]);
      float g  = tanh_(b2f(gp[r]) + bc[r]);
      float c  = fg * cp[r] + ig * g;
      cn[r] = c;
      cb[r] = f2b(c);
      rb[r] = f2b(tanh_(c));
    }
    *(f32x8_t*)(co_p + q * 8) = cn;
    *(u16x8_t*)(dc + q * 2048) = cb;
    *(u16x8_t*)(dr + q * 2048) = rb;
  }
}

// ==========================================================================
// gemm2h (R14): 128 rows x 256 cols per block, grid 512 = 128 rb x 4 cg.
// A-panel re-read factor 4 (was 8). 8 waves (2M x 4N), wave tile 64x64;
// dual acc (ocg kt<64, mt kt>=64) = 128 VGPR. LDS 3 x (A 8KB + B 16KB)
// = 72 KB; stage t+2, boundary vmcnt(3). A half-tile staging: thread t
// copies plane t>>7, row (rb&1)*128 + (t&127) of the 256-row packed tile.
// Epilogue: h = sigmoid(og_pre + ocg + bias_o) * (mt + xr), fp32 write.
// ==========================================================================
__global__ __launch_bounds__(512, 2) void gemm2h_kernel(
    const u16* __restrict__ A2p, const u16* __restrict__ W2q,
    const u16* __restrict__ G1, const float* __restrict__ bias_o,
    float* __restrict__ h_out) {
  constexpr int SLOT = 12288;  // u16: A 4096 + B 8192

  __shared__ u16 lds[3 * SLOT];  // 72 KiB

  int bid = blockIdx.x;          // grid = 512
  int cpx = gridDim.x >> 3;
  bid = (bid & 7) * cpx + (bid >> 3);

  int rb = bid >> 2, cg = bid & 3;
  int m0 = rb * 128, c0 = cg * 256;

  const int tid  = threadIdx.x;
  const int lane = tid & 63;
  const int wid  = tid >> 6;
  const int wr   = wid >> 2;     // 0..1 (64-row band)
  const int wc   = wid & 3;      // 0..3 (64-col band)
  const int hl16 = lane >> 4;
  const int l15  = lane & 15;

  // A staging: half of a 256-row packed tile (8KB): plane tid>>7, row tid&127
  const u16* pA = A2p + ((long)((rb >> 1) * 128)) * 8192
                + (tid >> 7) * 2048 + (rb & 1) * 1024 + (tid & 127) * 8;
  const u16* pB = W2q + ((long)(cg * 128)) * 8192 + tid * 8;
  const int dstg = tid * 8;  // u16

#define STAGE2(t, s) do { \
    gload16(pA + (long)(t) * 8192,        &lds[(s) * SLOT + dstg]); \
    gload16(pB + (long)(t) * 8192,        &lds[(s) * SLOT + 4096 + dstg]); \
    gload16(pB + (long)(t) * 8192 + 4096, &lds[(s) * SLOT + 8192 + dstg]); } while (0)

  // frag bases: A image plane stride 1024 (128 rows), B plane stride 2048 (256 cols)
  const int aoff = hl16 * 1024 + (wr * 64 + l15) * 8;          // + m*128
  const int boff = 4096 + hl16 * 2048 + (wc * 64 + l15) * 8;   // + n*128

  f32x4_t acc0[4][4], acc1[4][4];
#pragma unroll
  for (int m = 0; m < 4; ++m)
#pragma unroll
    for (int n = 0; n < 4; ++n) {
      acc0[m][n] = (f32x4_t){0.f, 0.f, 0.f, 0.f};
      acc1[m][n] = (f32x4_t){0.f, 0.f, 0.f, 0.f};
    }

  STAGE2(0, 0); STAGE2(1, 1);
  asm volatile("s_waitcnt vmcnt(3)" ::: "memory");
  __builtin_amdgcn_s_barrier();

  int slot = 0, s2 = 2;
  for (int t = 0; t < 128; ++t) {
    const u16* sA = &lds[slot * SLOT];
    const bool pre = (t + 2 < 128);
    if (pre) STAGE2(t + 2, s2);

    bf16x8_t wv[4], av[4];
#pragma unroll
    for (int n = 0; n < 4; ++n) wv[n] = *(const bf16x8_t*)&sA[boff + n * 128];
#pragma unroll
    for (int m = 0; m < 4; ++m) av[m] = *(const bf16x8_t*)&sA[aoff + m * 128];

    __builtin_amdgcn_s_setprio(1);
    if (t < 64) {
#pragma unroll
      for (int m = 0; m < 4; ++m)
#pragma unroll
        for (int n = 0; n < 4; ++n)
          acc0[m][n] = __builtin_amdgcn_mfma_f32_16x16x32_bf16(wv[n], av[m], acc0[m][n], 0, 0, 0);
    } else {
#pragma unroll
      for (int m = 0; m < 4; ++m)
#pragma unroll
        for (int n = 0; n < 4; ++n)
          acc1[m][n] = __builtin_amdgcn_mfma_f32_16x16x32_bf16(wv[n], av[m], acc1[m][n], 0, 0, 0);
    }
    __builtin_amdgcn_s_setprio(0);

    if (pre) asm volatile("s_waitcnt vmcnt(3)" ::: "memory");
    else     asm volatile("s_waitcnt vmcnt(0)" ::: "memory");
    __builtin_amdgcn_s_barrier();

    slot = (slot == 2) ? 0 : slot + 1;
    s2   = (s2   == 2) ? 0 : s2   + 1;
  }
#undef STAGE2

  // ---- fused h epilogue ----
  // rows = m0 + wr*64 + m*16 + l15 ; cols j = c0 + wc*64 + n*16 + 4*hl16 + r
#pragma unroll
  for (int m = 0; m < 4; ++m) {
    int row = m0 + wr * 64 + m * 16 + l15;
    const u16* g1r = G1 + (long)row * 8192;
#pragma unroll
    for (int n = 0; n < 4; ++n) {
      int jb = c0 + wc * 64 + n * 16 + 4 * hl16;
      u16x4_t og = *(const u16x4_t*)(g1r + 6144 + jb);
      u16x4_t xr = *(const u16x4_t*)(g1r + 7168 + jb);
      f32x4_t bo = *(const f32x4_t*)(bias_o + jb);
      f32x4_t h;
#pragma unroll
      for (int r = 0; r < 4; ++r) {
        float ogate = sigm_(acc0[m][n][r] + b2f(og[r]) + bo[r]);
        h[r] = ogate * (acc1[m][n][r] + b2f(xr[r]));
      }
      *(f32x4_t*)&h_out[(long)row * 1024 + jb] = h;
    }
  }
}

// ---------- launch ----------
extern "C" void kernel_launch(void* const* d_in, const int* in_sizes, int n_in,
                              void* d_out, int out_size, void* d_ws, size_t ws_size,
                              hipStream_t stream) {
  const float* x_t      = (const float*)d_in[0];
  const float* h_t      = (const float*)d_in[1];
  const float* c_t      = (const float*)d_in[2];
  const float* w_if_x   = (const float*)d_in[3];
  const float* w_if_h   = (const float*)d_in[4];
  const float* w_if_c   = (const float*)d_in[5];
  const float* bias_i   = (const float*)d_in[6];
  const float* bias_f   = (const float*)d_in[7];
  const float* w_c_x    = (const float*)d_in[8];
  const float* w_c_h    = (const float*)d_in[9];
  const float* bias_c   = (const float*)d_in[10];
  const float* w_o_x    = (const float*)d_in[11];
  const float* w_o_h    = (const float*)d_in[12];
  const float* w_o_c    = (const float*)d_in[13];
  const float* bias_o   = (const float*)d_in[14];
  const float* w_r_proj = (const float*)d_in[15];
  const float* w_r_x    = (const float*)d_in[16];

  char* ws = (char*)d_ws;
  u16* A1p  = (u16*)(ws);
  u16* W1tp = (u16*)(ws + 167772160L);
  u16* G1   = (u16*)(ws + 251658240L);
  u16* W2q  = (u16*)(ws + 520093696L);
  u16* A2p  = (u16*)(ws);               // aliases A1p (dead after GEMM1)

  float* h_out = (float*)d_out;
  float* c_out = h_out + 16384L * 1024L;

  // --- stage 0: single fused pack launch ---
  pack_all_kernel<<<dim3(100, 160), 256, 0, stream>>>(
      x_t, h_t, c_t, w_if_x, w_if_h, w_if_c, w_c_x, w_c_h,
      w_o_x, w_o_h, w_r_x, w_o_c, w_r_proj, A1p, W1tp, W2q);

  // --- stage 1: big fused GEMM -> all pre-activations ---
  gemm1_kernel<<<2048, 512, 0, stream>>>(A1p, W1tp, G1);

  // --- stage 2: elementwise gates -> c_new + packed A2 ---
  pass2_kernel<<<dim3(64, 64), 256, 0, stream>>>(G1, c_t, bias_i, bias_f, bias_c, c_out, A2p);

  // --- stage 3: fused [ocg|mt] GEMM + h epilogue (A-reuse x4) ---
  gemm2h_kernel<<<512, 512, 0, stream>>>(A2p, W2q, G1, bias_o, h_out);
}